// Round 4
// baseline (813.386 us; speedup 1.0000x reference)
//
#include <hip/hip_runtime.h>
#include <hip/hip_bf16.h>
#include <math.h>

// InvGraphConv: SplineCNN block on MI355X.
// N=20000, E=320000, D=3, KS=5 -> K=125, S=8, Fin=Fout=32, hidden=64.
//
// R4: atomic-free message passing. Edges counting-sorted by col (phase A:
// streaming z gather -> msg fp16, plain stores) and by row (phase B: CSR
// segmented register reduction + fused finalize). z stored fp16.

typedef short  s16x8 __attribute__((ext_vector_type(8)));
typedef float  f32x4 __attribute__((ext_vector_type(4)));

__device__ __forceinline__ unsigned short f2b(float f) {
    __hip_bfloat16 h = __float2bfloat16(f);
    return __builtin_bit_cast(unsigned short, h);
}
__device__ __forceinline__ float b2f(unsigned short u) {
    __hip_bfloat16 h = __builtin_bit_cast(__hip_bfloat16, u);
    return __bfloat162float(h);
}
__device__ __forceinline__ unsigned short f2h(float f) {
    _Float16 h = (_Float16)f;
    return __builtin_bit_cast(unsigned short, h);
}
__device__ __forceinline__ float h2f(unsigned short u) {
    _Float16 h = __builtin_bit_cast(_Float16, u);
    return (float)h;
}

__device__ __forceinline__ int swzblk() {
    int b = blockIdx.x, n = gridDim.x;
    if ((n & 7) == 0) { int q = n >> 3; b = (b & 7) * q + (b >> 3); }
    return b;
}

__device__ __forceinline__ void spline8(const float u0, const float u1, const float u2,
                                        float* __restrict__ b, int* __restrict__ id) {
    const float u[3] = {u0, u1, u2};
    const int strides[3] = {25, 5, 1};
    float fr[3];
    int   i0[3];
#pragma unroll
    for (int d = 0; d < 3; ++d) {
        float p = u[d] * 4.0f;
        float f = floorf(p);
        f = fminf(fmaxf(f, 0.0f), 3.0f);
        i0[d] = (int)f;
        fr[d] = p - f;
    }
#pragma unroll
    for (int s = 0; s < 8; ++s) {
        float bb = 1.0f;
        int   ii = 0;
#pragma unroll
        for (int d = 0; d < 3; ++d) {
            int c = (s >> d) & 1;
            bb *= c ? fr[d] : (1.0f - fr[d]);
            ii += (i0[d] + c) * strides[d];
        }
        b[s] = bb;
        id[s] = ii;
    }
}

__global__ void hist_kernel(const int* __restrict__ row, const int* __restrict__ col,
                            int* __restrict__ histR, int* __restrict__ histC, int E) {
    int e = blockIdx.x * blockDim.x + threadIdx.x;
    if (e >= E) return;
    atomicAdd(&histR[row[e]], 1);
    atomicAdd(&histC[col[e]], 1);
}

// single-block exclusive scan of hist[N] -> out1[N] (and optional copy out2)
__global__ __launch_bounds__(1024) void scan_kernel(const int* __restrict__ hist,
                                                    int* __restrict__ out1,
                                                    int* __restrict__ out2, int N) {
    __shared__ int wsum[16];
    __shared__ int carry;
    int t = threadIdx.x, lane = t & 63, w = t >> 6;
    if (t == 0) carry = 0;
    __syncthreads();
    for (int base = 0; base < N; base += 1024) {
        int i = base + t;
        int v = (i < N) ? hist[i] : 0;
        int sc = v;
#pragma unroll
        for (int off = 1; off < 64; off <<= 1) {
            int u = __shfl_up(sc, off);
            if (lane >= off) sc += u;
        }
        if (lane == 63) wsum[w] = sc;
        __syncthreads();
        if (w == 0 && lane < 16) {
            int s = wsum[lane];
#pragma unroll
            for (int off = 1; off < 16; off <<= 1) {
                int u = __shfl_up(s, off);
                if (lane >= off) s += u;
            }
            wsum[lane] = s;
        }
        __syncthreads();
        int woff = (w > 0 ? wsum[w - 1] : 0) + carry;
        int excl = woff + sc - v;
        if (i < N) {
            out1[i] = excl;
            if (out2) out2[i] = excl;
        }
        __syncthreads();
        if (t == 0) carry += wsum[15];
        __syncthreads();
    }
}

// dual scatter: jc = col-sorted slot (msg layout), jr = row-sorted slot.
// perm[jr] = jc lets phase B walk rows and find col-sorted msgs.
__global__ void scatter_kernel(const int* __restrict__ row, const int* __restrict__ col,
                               int* __restrict__ cursorC, int* __restrict__ cursorR,
                               int* __restrict__ jpos, int* __restrict__ colS,
                               int* __restrict__ perm, int E) {
    int e = blockIdx.x * blockDim.x + threadIdx.x;
    if (e >= E) return;
    int c = col[e], r = row[e];
    int jc = atomicAdd(&cursorC[c], 1);
    int jr = atomicAdd(&cursorR[r], 1);
    jpos[e] = jc;
    colS[jc] = c;
    perm[jr] = jc;
}

__global__ void deg_float_kernel(const int* __restrict__ histR, float* __restrict__ deg, int N) {
    int n = blockIdx.x * blockDim.x + threadIdx.x;
    if (n < N) deg[n] = (float)histR[n];
}

__global__ void basis1_kernel(const float* __restrict__ pseudo, const int* __restrict__ jpos,
                              float* __restrict__ basis, int* __restrict__ idx, int E) {
    int e = blockIdx.x * blockDim.x + threadIdx.x;
    if (e >= E) return;
    float b[8]; int id[8];
    spline8(pseudo[e * 3 + 0], pseudo[e * 3 + 1], pseudo[e * 3 + 2], b, id);
    int j = jpos ? jpos[e] : e;
#pragma unroll
    for (int s = 0; s < 8; ++s) { basis[j * 8 + s] = b[s]; idx[j * 8 + s] = id[s]; }
}

__global__ void basis2_kernel(const float* __restrict__ pseudo, const float* __restrict__ t,
                              const int* __restrict__ row, const int* __restrict__ col,
                              const int* __restrict__ jpos,
                              float* __restrict__ basis, int* __restrict__ idx, int E) {
    int e = blockIdx.x * blockDim.x + threadIdx.x;
    if (e >= E) return;
    int r = row[e], c = col[e];
    float u[3];
#pragma unroll
    for (int d = 0; d < 3; ++d) {
        float v = pseudo[e * 3 + d] + t[c * 3 + d] - t[r * 3 + d];
        u[d] = fminf(fmaxf(v, 0.0f), 1.0f);
    }
    float b[8]; int id[8];
    spline8(u[0], u[1], u[2], b, id);
    int j = jpos ? jpos[e] : e;
#pragma unroll
    for (int s = 0; s < 8; ++s) { basis[j * 8 + s] = b[s]; idx[j * 8 + s] = id[s]; }
}

// conv1 phase A: msg1[j,o] = sum_s b_s * W1[k_s, o]  (W1 is 32KB, cache-hot)
__global__ __launch_bounds__(256) void msgA1_kernel(
        const float* __restrict__ basis, const int* __restrict__ idx,
        const float* __restrict__ W1, unsigned short* __restrict__ msg, int E) {
    int j = blockIdx.x * 4 + (threadIdx.x >> 6);
    if (j >= E) return;
    int l = threadIdx.x & 63;
    const float4* bp = (const float4*)(basis + (size_t)j * 8);
    const int4*   ip = (const int4*)(idx + (size_t)j * 8);
    float4 b0 = bp[0], b1 = bp[1];
    int4   i0 = ip[0], i1 = ip[1];
    float bv[8] = {b0.x, b0.y, b0.z, b0.w, b1.x, b1.y, b1.z, b1.w};
    int   kv[8] = {i0.x, i0.y, i0.z, i0.w, i1.x, i1.y, i1.z, i1.w};
    float m = 0.0f;
#pragma unroll
    for (int s = 0; s < 8; ++s) m += bv[s] * W1[kv[s] * 64 + l];
    msg[(size_t)j * 64 + l] = f2h(m);
}

// conv2 phase A: msg[j,o] = sum_s b_s * z2[colS[j], k_s*64+o], streaming store.
__global__ __launch_bounds__(256) void msgA2_kernel(
        const unsigned short* __restrict__ z, const float* __restrict__ basis,
        const int* __restrict__ idx, const int* __restrict__ colS,
        unsigned short* __restrict__ msg, int E) {
    int b = swzblk();
    int j = b * 4 + (threadIdx.x >> 6);
    if (j >= E) return;
    int l = threadIdx.x & 63;
    const float4* bp = (const float4*)(basis + (size_t)j * 8);
    const int4*   ip = (const int4*)(idx + (size_t)j * 8);
    float4 b0 = bp[0], b1 = bp[1];
    int4   i0 = ip[0], i1 = ip[1];
    float bv[8] = {b0.x, b0.y, b0.z, b0.w, b1.x, b1.y, b1.z, b1.w};
    int   kv[8] = {i0.x, i0.y, i0.z, i0.w, i1.x, i1.y, i1.z, i1.w};
    size_t zb = (size_t)colS[j] * 8000;
    float m = 0.0f;
#pragma unroll
    for (int s = 0; s < 8; ++s) m += bv[s] * h2f(z[zb + (size_t)kv[s] * 64 + l]);
    msg[(size_t)j * 64 + l] = f2h(m);
}

// conv3 phase A: half-wave per edge, 32 channels.
__global__ __launch_bounds__(256) void msgA3_kernel(
        const unsigned short* __restrict__ z, const float* __restrict__ basis,
        const int* __restrict__ idx, const int* __restrict__ colS,
        unsigned short* __restrict__ msg, int E) {
    int b = swzblk();
    int j = b * 8 + (threadIdx.x >> 5);
    if (j >= E) return;
    int l = threadIdx.x & 31;
    const float4* bp = (const float4*)(basis + (size_t)j * 8);
    const int4*   ip = (const int4*)(idx + (size_t)j * 8);
    float4 b0 = bp[0], b1 = bp[1];
    int4   i0 = ip[0], i1 = ip[1];
    float bv[8] = {b0.x, b0.y, b0.z, b0.w, b1.x, b1.y, b1.z, b1.w};
    int   kv[8] = {i0.x, i0.y, i0.z, i0.w, i1.x, i1.y, i1.z, i1.w};
    size_t zb = (size_t)colS[j] * 4000;
    float m = 0.0f;
#pragma unroll
    for (int s = 0; s < 8; ++s) m += bv[s] * h2f(z[zb + (size_t)kv[s] * 32 + l]);
    msg[(size_t)j * 32 + l] = f2h(m);
}

// phase B, 64 channels: wave per row-node; CSR walk of perm; fused finalize.
__global__ __launch_bounds__(256) void phaseB64_kernel(
        const unsigned short* __restrict__ msg, const int* __restrict__ perm,
        const int* __restrict__ rowStart, const int* __restrict__ histR,
        const float* __restrict__ bias, unsigned short* __restrict__ outB,
        float* __restrict__ outF, int N, int do_elu) {
    int n = blockIdx.x * 4 + (threadIdx.x >> 6);
    if (n >= N) return;
    int l = threadIdx.x & 63;
    int s0 = rowStart[n];
    int cntT = histR[n];
    float a = 0.0f;
    for (int base = 0; base < cntT; base += 64) {
        int c = cntT - base < 64 ? cntT - base : 64;
        int pv = (l < c) ? perm[s0 + base + l] : 0;
        for (int i = 0; i < c; ++i) {
            int slot = __shfl(pv, i);
            a += h2f(msg[(size_t)slot * 64 + l]);
        }
    }
    float v = a / fmaxf((float)cntT, 1.0f) + bias[l];
    if (do_elu) v = (v > 0.0f) ? v : (expf(v) - 1.0f);
    if (outB) outB[(size_t)n * 64 + l] = f2b(v);
    if (outF) outF[(size_t)n * 64 + l] = v;
}

// phase B, 32 channels: half-wave per row-node; writes fp32 out (+bias, no elu).
__global__ __launch_bounds__(256) void phaseB32_kernel(
        const unsigned short* __restrict__ msg, const int* __restrict__ perm,
        const int* __restrict__ rowStart, const int* __restrict__ histR,
        const float* __restrict__ bias, float* __restrict__ out, int N) {
    int n = blockIdx.x * 8 + (threadIdx.x >> 5);
    if (n >= N) return;
    int l = threadIdx.x & 31;
    int s0 = rowStart[n];
    int cntT = histR[n];
    float a = 0.0f;
    for (int base = 0; base < cntT; base += 32) {
        int c = cntT - base < 32 ? cntT - base : 32;
        int pv = (l < c) ? perm[s0 + base + l] : 0;
        for (int i = 0; i < c; ++i) {
            int slot = __shfl(pv, i, 32);
            a += h2f(msg[(size_t)slot * 32 + l]);
        }
    }
    out[(size_t)n * 32 + l] = a / fmaxf((float)cntT, 1.0f) + bias[l];
}

__global__ void castbf_kernel(const float* __restrict__ in, unsigned short* __restrict__ out,
                              int n) {
    int t = blockIdx.x * blockDim.x + threadIdx.x;
    if (t < n) out[t] = f2b(in[t]);
}

// Pack W [Kc][Fin][Fout] (fp32) into MFMA B-fragment order (bf16).
__global__ void pack_w_kernel(const float* __restrict__ W, unsigned short* __restrict__ BF,
                              int Kc, int Fin, int Fout, int ksteps) {
    int t = blockIdx.x * blockDim.x + threadIdx.x;
    int total = Kc * Fout * Fin;
    if (t >= total) return;
    int c = t / Fin;
    int i = t % Fin;
    int kk = c / Fout, o = c % Fout;
    int ct = c >> 4, lr = c & 15;
    int step = i >> 5, rem = i & 31, lg = rem >> 3, jj = rem & 7;
    size_t dst = ((((size_t)ct * ksteps + step) * 4 + lg) * 16 + lr) * 8 + jj;
    BF[dst] = f2b(W[((size_t)kk * Fin + i) * Fout + o]);
}

// z = A @ B via mfma_f32_16x16x32_bf16. OUT_MODE: 0=f32, 2=f16.
template<int KSTEPS, int OUT_MODE>
__global__ __launch_bounds__(256) void zgemm_kernel(
        const unsigned short* __restrict__ A, int M,
        const unsigned short* __restrict__ BF,
        void* __restrict__ Z, int zld, int ct0, int zct) {
    int w = threadIdx.x >> 6, l = threadIdx.x & 63;
    int m0 = blockIdx.x * 64 + w * 16;
    int lr = l & 15, lg = l >> 4;
    const int KD = KSTEPS * 32;
    f32x4 acc[4];
#pragma unroll
    for (int cf = 0; cf < 4; ++cf) acc[cf] = (f32x4){0.f, 0.f, 0.f, 0.f};
    int arow = m0 + lr; if (arow > M - 1) arow = M - 1;
#pragma unroll
    for (int step = 0; step < KSTEPS; ++step) {
        s16x8 a = *(const s16x8*)(A + (size_t)arow * KD + step * 32 + lg * 8);
#pragma unroll
        for (int cf = 0; cf < 4; ++cf) {
            int ctl = blockIdx.y * 4 + cf;
            if (ctl < zct) {
                int ctg = ct0 + ctl;
                const unsigned short* bp =
                    BF + ((((size_t)ctg * KSTEPS + step) * 4 + lg) * 16 + lr) * 8;
                s16x8 b = *(const s16x8*)bp;
                acc[cf] = __builtin_amdgcn_mfma_f32_16x16x32_bf16(a, b, acc[cf], 0, 0, 0);
            }
        }
    }
#pragma unroll
    for (int cf = 0; cf < 4; ++cf) {
        int ctl = blockIdx.y * 4 + cf;
        if (ctl >= zct) continue;
        int colc = ctl * 16 + lr;
#pragma unroll
        for (int r = 0; r < 4; ++r) {
            int rowc = m0 + lg * 4 + r;
            if (rowc < M) {
                if (OUT_MODE == 2)
                    ((unsigned short*)Z)[(size_t)rowc * zld + colc] = f2h(acc[cf][r]);
                else
                    ((float*)Z)[(size_t)rowc * zld + colc] = acc[cf][r];
            }
        }
    }
}

// ---- fallback kernels (ws too small for full z): atomic gathers, unsorted ----
__global__ __launch_bounds__(256) void conv1_at_kernel(
        const float* __restrict__ basis, const int* __restrict__ idx,
        const int* __restrict__ row, const float* __restrict__ W1,
        float* __restrict__ acc, int E) {
    int j = blockIdx.x * 4 + (threadIdx.x >> 6);
    if (j >= E) return;
    int l = threadIdx.x & 63;
    float m = 0.0f;
#pragma unroll
    for (int s = 0; s < 8; ++s) m += basis[j * 8 + s] * W1[idx[j * 8 + s] * 64 + l];
    atomicAdd(&acc[(size_t)row[j] * 64 + l], m);
}

__global__ __launch_bounds__(256) void gather2_at_kernel(
        const unsigned short* __restrict__ z, int zld,
        const float* __restrict__ basis, const int* __restrict__ idx,
        const int* __restrict__ row, const int* __restrict__ col,
        float* __restrict__ acc, int E, int k0, int k1) {
    int j = blockIdx.x * 4 + (threadIdx.x >> 6);
    if (j >= E) return;
    int l = threadIdx.x & 63;
    size_t zb = (size_t)col[j] * zld;
    float m = 0.0f; bool any = false;
#pragma unroll
    for (int s = 0; s < 8; ++s) {
        int k = idx[j * 8 + s];
        if (k >= k0 && k < k1) { m += basis[j * 8 + s] * h2f(z[zb + (size_t)(k - k0) * 64 + l]); any = true; }
    }
    if (any) atomicAdd(&acc[(size_t)row[j] * 64 + l], m);
}

__global__ __launch_bounds__(256) void gather3_at_kernel(
        const unsigned short* __restrict__ z, int zld,
        const float* __restrict__ basis, const int* __restrict__ idx,
        const int* __restrict__ row, const int* __restrict__ col,
        float* __restrict__ acc, int E, int k0, int k1) {
    int j = blockIdx.x * 8 + (threadIdx.x >> 5);
    if (j >= E) return;
    int l = threadIdx.x & 31;
    size_t zb = (size_t)col[j] * zld;
    float m = 0.0f; bool any = false;
#pragma unroll
    for (int s = 0; s < 8; ++s) {
        int k = idx[j * 8 + s];
        if (k >= k0 && k < k1) { m += basis[j * 8 + s] * h2f(z[zb + (size_t)(k - k0) * 32 + l]); any = true; }
    }
    if (any) atomicAdd(&acc[(size_t)row[j] * 32 + l], m);
}

__global__ void finalize_kernel(const float* __restrict__ acc, const float* __restrict__ deg,
                                const float* __restrict__ bias, float* __restrict__ outF,
                                unsigned short* __restrict__ outB,
                                int N, int F, int do_elu) {
    int t = blockIdx.x * blockDim.x + threadIdx.x;
    if (t >= N * F) return;
    int n = t / F, o = t % F;
    float v = acc[t] / fmaxf(deg[n], 1.0f) + bias[o];
    if (do_elu) v = (v > 0.0f) ? v : (expf(v) - 1.0f);
    if (outF) outF[t] = v;
    if (outB) outB[t] = f2b(v);
}

// stn3 + stn4 per node
__global__ __launch_bounds__(64) void stn34_kernel(
        const float* __restrict__ h2, const float* __restrict__ w3,
        const float* __restrict__ b3, const float* __restrict__ w4,
        const float* __restrict__ b4, float* __restrict__ t, int N) {
    int n = blockIdx.x;
    int o = threadIdx.x;
    __shared__ float sh[64];
    __shared__ float sh3[64];
    sh[o] = h2[n * 64 + o];
    __syncthreads();
    float v = b3[o];
#pragma unroll
    for (int i = 0; i < 64; ++i) v += sh[i] * w3[i * 64 + o];
    v = (v > 0.0f) ? v : (expf(v) - 1.0f);
    sh3[o] = v;
    __syncthreads();
    if (o < 3) {
        float tv = b4[o];
#pragma unroll
        for (int i = 0; i < 64; ++i) tv += sh3[i] * w4[i * 3 + o];
        t[n * 3 + o] = tv;
    }
}

extern "C" void kernel_launch(void* const* d_in, const int* in_sizes, int n_in,
                              void* d_out, int out_size, void* d_ws, size_t ws_size,
                              hipStream_t stream) {
    const float* x      = (const float*)d_in[0];
    const int*   ei     = (const int*)d_in[1];
    const float* pseudo = (const float*)d_in[2];
    const float* w1     = (const float*)d_in[3];
    const float* b1     = (const float*)d_in[4];
    const float* w2     = (const float*)d_in[5];
    const float* b2     = (const float*)d_in[6];
    const float* w3     = (const float*)d_in[7];
    const float* b3     = (const float*)d_in[8];
    const float* w4     = (const float*)d_in[9];
    const float* b4     = (const float*)d_in[10];
    const float* wc     = (const float*)d_in[11];
    const float* cb     = (const float*)d_in[12];
    float* out = (float*)d_out;

    const int N = in_sizes[0] / 32;
    const int E = in_sizes[1] / 2;
    const int* row = ei;
    const int* col = ei + E;
    const int KC = 125;

    char* p = (char*)d_ws;
    // zeroed region: histograms only
    int* histR = (int*)p; p += (size_t)N * sizeof(int);
    int* histC = (int*)p; p += (size_t)N * sizeof(int);
    size_t zero_bytes = (size_t)(p - (char*)d_ws);
    // non-zeroed
    int* cursorC  = (int*)p; p += (size_t)N * sizeof(int);
    int* cursorR  = (int*)p; p += (size_t)N * sizeof(int);
    int* rowStart = (int*)p; p += (size_t)N * sizeof(int);
    int* jpos = (int*)p; p += (size_t)E * sizeof(int);
    int* colS = (int*)p; p += (size_t)E * sizeof(int);
    int* perm = (int*)p; p += (size_t)E * sizeof(int);
    float* h2 = (float*)p; p += (size_t)N * 64 * sizeof(float);
    float* tt = (float*)p; p += (size_t)N * 3 * sizeof(float);
    float* basis = (float*)p; p += (size_t)E * 8 * sizeof(float);
    int*   idx   = (int*)p;  p += (size_t)E * 8 * sizeof(int);
    unsigned short* h1b = (unsigned short*)p; p += (size_t)N * 64 * sizeof(short);
    unsigned short* xb  = (unsigned short*)p; p += (size_t)N * 32 * sizeof(short);
    unsigned short* BF2 = (unsigned short*)p; p += (size_t)KC * 64 * 64 * sizeof(short);
    unsigned short* BF3 = (unsigned short*)p; p += (size_t)KC * 32 * 32 * sizeof(short);
    unsigned short* msg = (unsigned short*)p; p += (size_t)E * 64 * sizeof(short);
    size_t fixed = (size_t)(p - (char*)d_ws);
    size_t zcap = (ws_size > fixed) ? (ws_size - fixed) : 0;

    const size_t z2_full = (size_t)N * KC * 64 * sizeof(short);
    const size_t z3_full = (size_t)N * KC * 32 * sizeof(short);
    bool full = (zcap >= z2_full) && (zcap >= z3_full);
    void* zbuf = (void*)p;

    hipMemsetAsync(d_ws, 0, zero_bytes, stream);

    pack_w_kernel<<<(KC * 64 * 64 + 255) / 256, 256, 0, stream>>>(w2, BF2, KC, 64, 64, 2);
    pack_w_kernel<<<(KC * 32 * 32 + 255) / 256, 256, 0, stream>>>(wc, BF3, KC, 32, 32, 1);
    castbf_kernel<<<(N * 32 + 255) / 256, 256, 0, stream>>>(x, xb, N * 32);

    hist_kernel<<<(E + 255) / 256, 256, 0, stream>>>(row, col, histR, histC, E);

    const int MT = (N + 63) / 64;

    if (full) {
        // ---- fast path: dual sort, atomic-free ----
        scan_kernel<<<1, 1024, 0, stream>>>(histC, cursorC, nullptr, N);
        scan_kernel<<<1, 1024, 0, stream>>>(histR, rowStart, cursorR, N);
        scatter_kernel<<<(E + 255) / 256, 256, 0, stream>>>(row, col, cursorC, cursorR,
                                                            jpos, colS, perm, E);
        basis1_kernel<<<(E + 255) / 256, 256, 0, stream>>>(pseudo, jpos, basis, idx, E);

        // conv1
        msgA1_kernel<<<(E + 3) / 4, 256, 0, stream>>>(basis, idx, w1, msg, E);
        phaseB64_kernel<<<(N + 3) / 4, 256, 0, stream>>>(msg, perm, rowStart, histR,
                                                         b1, h1b, nullptr, N, 1);
        // conv2
        {
            dim3 g(MT, KC);
            zgemm_kernel<2, 2><<<g, 256, 0, stream>>>(h1b, N, BF2, zbuf, KC * 64, 0, KC * 4);
            msgA2_kernel<<<(E + 3) / 4, 256, 0, stream>>>(
                (const unsigned short*)zbuf, basis, idx, colS, msg, E);
            phaseB64_kernel<<<(N + 3) / 4, 256, 0, stream>>>(msg, perm, rowStart, histR,
                                                             b2, nullptr, h2, N, 1);
        }
        stn34_kernel<<<N, 64, 0, stream>>>(h2, w3, b3, w4, b4, tt, N);
        basis2_kernel<<<(E + 255) / 256, 256, 0, stream>>>(pseudo, tt, row, col, jpos, basis, idx, E);
        // conv3
        {
            dim3 g(MT, (KC * 32 + 63) / 64);
            zgemm_kernel<1, 2><<<g, 256, 0, stream>>>(xb, N, BF3, zbuf, KC * 32, 0, KC * 2);
            msgA3_kernel<<<(E + 7) / 8, 256, 0, stream>>>(
                (const unsigned short*)zbuf, basis, idx, colS, msg, E);
            phaseB32_kernel<<<(N + 7) / 8, 256, 0, stream>>>(msg, perm, rowStart, histR,
                                                             cb, out, N);
        }
    } else {
        // ---- fallback: chunked z + atomic gathers (unsorted) ----
        // alias accumulators into msg area (needs 12.9MB <= 41MB)
        float* deg  = (float*)msg;
        float* acc1 = deg  + N;
        float* acc2 = acc1 + (size_t)N * 64;
        float* acc3 = acc2 + (size_t)N * 64;
        size_t acc_bytes = ((size_t)N * (1 + 64 + 64 + 32)) * sizeof(float);
        hipMemsetAsync((void*)msg, 0, acc_bytes, stream);
        deg_float_kernel<<<(N + 255) / 256, 256, 0, stream>>>(histR, deg, N);

        int KC2 = (int)(zcap / ((size_t)N * 64 * sizeof(short))); if (KC2 > KC) KC2 = KC;
        int KC3 = (int)(zcap / ((size_t)N * 32 * sizeof(short))); if (KC3 > KC) KC3 = KC;
        if (KC2 < 1) KC2 = 1;
        if (KC3 < 1) KC3 = 1;

        basis1_kernel<<<(E + 255) / 256, 256, 0, stream>>>(pseudo, nullptr, basis, idx, E);
        conv1_at_kernel<<<(E + 3) / 4, 256, 0, stream>>>(basis, idx, row, w1, acc1, E);
        finalize_kernel<<<(N * 64 + 255) / 256, 256, 0, stream>>>(acc1, deg, b1, nullptr, h1b, N, 64, 1);
        for (int k0 = 0; k0 < KC; k0 += KC2) {
            int kc = KC - k0 < KC2 ? KC - k0 : KC2;
            dim3 g(MT, kc);
            zgemm_kernel<2, 2><<<g, 256, 0, stream>>>(h1b, N, BF2, zbuf, kc * 64, k0 * 4, kc * 4);
            gather2_at_kernel<<<(E + 3) / 4, 256, 0, stream>>>(
                (const unsigned short*)zbuf, kc * 64, basis, idx, row, col, acc2, E, k0, k0 + kc);
        }
        finalize_kernel<<<(N * 64 + 255) / 256, 256, 0, stream>>>(acc2, deg, b2, h2, nullptr, N, 64, 1);
        stn34_kernel<<<N, 64, 0, stream>>>(h2, w3, b3, w4, b4, tt, N);
        basis2_kernel<<<(E + 255) / 256, 256, 0, stream>>>(pseudo, tt, row, col, nullptr, basis, idx, E);
        for (int k0 = 0; k0 < KC; k0 += KC3) {
            int kc = KC - k0 < KC3 ? KC - k0 : KC3;
            dim3 g(MT, (kc * 32 + 63) / 64);
            zgemm_kernel<1, 2><<<g, 256, 0, stream>>>(xb, N, BF3, zbuf, kc * 32, k0 * 2, kc * 2);
            gather3_at_kernel<<<(E + 7) / 8, 256, 0, stream>>>(
                (const unsigned short*)zbuf, kc * 32, basis, idx, row, col, acc3, E, k0, k0 + kc);
        }
        finalize_kernel<<<(N * 32 + 255) / 256, 256, 0, stream>>>(acc3, deg, cb, out, nullptr, N, 32, 0);
    }
}

// Round 5
// 560.395 us; speedup vs baseline: 1.4514x; 1.4514x over previous
//
#include <hip/hip_runtime.h>
#include <hip/hip_bf16.h>
#include <math.h>

// InvGraphConv: SplineCNN block on MI355X.
// N=20000, E=320000, D=3, KS=5 -> K=125, S=8, Fin=Fout=32, hidden=64.
//
// R5: atomic-free dual-sort message passing, fitted to ws via CHANNEL-split z
// (no k-guard, no RMW). Phase A: LDS-staged streaming z gather -> msg fp16.
// Phase B: row-CSR register reduction + fused finalize. conv1 fully fused
// into phase B (W1 in LDS). idx as u8, z/msg fp16.

typedef short  s16x8 __attribute__((ext_vector_type(8)));
typedef float  f32x4 __attribute__((ext_vector_type(4)));

__device__ __forceinline__ unsigned short f2b(float f) {
    __hip_bfloat16 h = __float2bfloat16(f);
    return __builtin_bit_cast(unsigned short, h);
}
__device__ __forceinline__ unsigned short f2h(float f) {
    _Float16 h = (_Float16)f;
    return __builtin_bit_cast(unsigned short, h);
}
__device__ __forceinline__ float h2f(unsigned short u) {
    _Float16 h = __builtin_bit_cast(_Float16, u);
    return (float)h;
}

__device__ __forceinline__ void spline8(const float u0, const float u1, const float u2,
                                        float* __restrict__ b, int* __restrict__ id) {
    const float u[3] = {u0, u1, u2};
    const int strides[3] = {25, 5, 1};
    float fr[3];
    int   i0[3];
#pragma unroll
    for (int d = 0; d < 3; ++d) {
        float p = u[d] * 4.0f;
        float f = floorf(p);
        f = fminf(fmaxf(f, 0.0f), 3.0f);
        i0[d] = (int)f;
        fr[d] = p - f;
    }
#pragma unroll
    for (int s = 0; s < 8; ++s) {
        float bb = 1.0f;
        int   ii = 0;
#pragma unroll
        for (int d = 0; d < 3; ++d) {
            int c = (s >> d) & 1;
            bb *= c ? fr[d] : (1.0f - fr[d]);
            ii += (i0[d] + c) * strides[d];
        }
        b[s] = bb;
        id[s] = ii;
    }
}

__global__ void hist_kernel(const int* __restrict__ row, const int* __restrict__ col,
                            int* __restrict__ histR, int* __restrict__ histC, int E) {
    int e = blockIdx.x * blockDim.x + threadIdx.x;
    if (e >= E) return;
    atomicAdd(&histR[row[e]], 1);
    atomicAdd(&histC[col[e]], 1);
}

// single-block exclusive scan of hist[N] -> out1 (and optional copy out2)
__global__ __launch_bounds__(1024) void scan_kernel(const int* __restrict__ hist,
                                                    int* __restrict__ out1,
                                                    int* __restrict__ out2, int N) {
    __shared__ int wsum[16];
    __shared__ int carry;
    int t = threadIdx.x, lane = t & 63, w = t >> 6;
    if (t == 0) carry = 0;
    __syncthreads();
    for (int base = 0; base < N; base += 1024) {
        int i = base + t;
        int v = (i < N) ? hist[i] : 0;
        int sc = v;
#pragma unroll
        for (int off = 1; off < 64; off <<= 1) {
            int u = __shfl_up(sc, off);
            if (lane >= off) sc += u;
        }
        if (lane == 63) wsum[w] = sc;
        __syncthreads();
        if (w == 0 && lane < 16) {
            int s = wsum[lane];
#pragma unroll
            for (int off = 1; off < 16; off <<= 1) {
                int u = __shfl_up(s, off);
                if (lane >= off) s += u;
            }
            wsum[lane] = s;
        }
        __syncthreads();
        int woff = (w > 0 ? wsum[w - 1] : 0) + carry;
        int excl = woff + sc - v;
        if (i < N) {
            out1[i] = excl;
            if (out2) out2[i] = excl;
        }
        __syncthreads();
        if (t == 0) carry += wsum[15];
        __syncthreads();
    }
}

// dual scatter: jc = col-sorted slot, jr = row-sorted slot; perm[jr]=jc.
__global__ void scatter_kernel(const int* __restrict__ row, const int* __restrict__ col,
                               int* __restrict__ cursorC, int* __restrict__ cursorR,
                               int* __restrict__ jpos, int* __restrict__ colS,
                               int* __restrict__ perm, int E) {
    int e = blockIdx.x * blockDim.x + threadIdx.x;
    if (e >= E) return;
    int c = col[e], r = row[e];
    int jc = atomicAdd(&cursorC[c], 1);
    int jr = atomicAdd(&cursorR[r], 1);
    jpos[e] = jc;
    colS[jc] = c;
    perm[jr] = jc;
}

__global__ void basis1_kernel(const float* __restrict__ pseudo, const int* __restrict__ jpos,
                              float* __restrict__ basis, unsigned char* __restrict__ idxb, int E) {
    int e = blockIdx.x * blockDim.x + threadIdx.x;
    if (e >= E) return;
    float b[8]; int id[8];
    spline8(pseudo[e * 3 + 0], pseudo[e * 3 + 1], pseudo[e * 3 + 2], b, id);
    int j = jpos ? jpos[e] : e;
#pragma unroll
    for (int s = 0; s < 8; ++s) { basis[(size_t)j * 8 + s] = b[s]; idxb[(size_t)j * 8 + s] = (unsigned char)id[s]; }
}

__global__ void basis2_kernel(const float* __restrict__ pseudo, const float* __restrict__ t,
                              const int* __restrict__ row, const int* __restrict__ col,
                              const int* __restrict__ jpos,
                              float* __restrict__ basis, unsigned char* __restrict__ idxb, int E) {
    int e = blockIdx.x * blockDim.x + threadIdx.x;
    if (e >= E) return;
    int r = row[e], c = col[e];
    float u[3];
#pragma unroll
    for (int d = 0; d < 3; ++d) {
        float v = pseudo[e * 3 + d] + t[c * 3 + d] - t[r * 3 + d];
        u[d] = fminf(fmaxf(v, 0.0f), 1.0f);
    }
    float b[8]; int id[8];
    spline8(u[0], u[1], u[2], b, id);
    int j = jpos ? jpos[e] : e;
#pragma unroll
    for (int s = 0; s < 8; ++s) { basis[(size_t)j * 8 + s] = b[s]; idxb[(size_t)j * 8 + s] = (unsigned char)id[s]; }
}

__global__ void castbf_kernel(const float* __restrict__ in, unsigned short* __restrict__ out,
                              int n) {
    int t = blockIdx.x * blockDim.x + threadIdx.x;
    if (t < n) out[t] = f2b(in[t]);
}

// Pack W [Kc][Fin][Fout] fp32 -> MFMA B-fragments bf16, channel-split order:
// global col c' = (o/CH)*(Kc*CH) + k*CH + o%CH.
__global__ void pack_w_kernel(const float* __restrict__ W, unsigned short* __restrict__ BF,
                              int Kc, int Fin, int Fout, int ksteps, int CH) {
    int t = blockIdx.x * blockDim.x + threadIdx.x;
    int total = Kc * Fout * Fin;
    if (t >= total) return;
    int c = t / Fin;
    int i = t % Fin;
    int kk = c / Fout, o = c % Fout;
    int split = o / CH;
    int cp = split * (Kc * CH) + kk * CH + (o % CH);
    int ct = cp >> 4, lr = cp & 15;
    int step = i >> 5, rem = i & 31, lg = rem >> 3, jj = rem & 7;
    size_t dst = ((((size_t)ct * ksteps + step) * 4 + lg) * 16 + lr) * 8 + jj;
    BF[dst] = f2b(W[((size_t)kk * Fin + i) * Fout + o]);
}

// z = A @ B via mfma_f32_16x16x32_bf16 -> fp16 Z [M][zld]; ct0 = col-tile base.
template<int KSTEPS>
__global__ __launch_bounds__(256) void zgemm_kernel(
        const unsigned short* __restrict__ A, int M,
        const unsigned short* __restrict__ BF,
        unsigned short* __restrict__ Z, int zld, int ct0, int zct) {
    int w = threadIdx.x >> 6, l = threadIdx.x & 63;
    int m0 = blockIdx.x * 64 + w * 16;
    int lr = l & 15, lg = l >> 4;
    const int KD = KSTEPS * 32;
    f32x4 acc[4];
#pragma unroll
    for (int cf = 0; cf < 4; ++cf) acc[cf] = (f32x4){0.f, 0.f, 0.f, 0.f};
    int arow = m0 + lr; if (arow > M - 1) arow = M - 1;
#pragma unroll
    for (int step = 0; step < KSTEPS; ++step) {
        s16x8 a = *(const s16x8*)(A + (size_t)arow * KD + step * 32 + lg * 8);
#pragma unroll
        for (int cf = 0; cf < 4; ++cf) {
            int ctl = blockIdx.y * 4 + cf;
            if (ctl < zct) {
                int ctg = ct0 + ctl;
                const unsigned short* bp =
                    BF + ((((size_t)ctg * KSTEPS + step) * 4 + lg) * 16 + lr) * 8;
                s16x8 b = *(const s16x8*)bp;
                acc[cf] = __builtin_amdgcn_mfma_f32_16x16x32_bf16(a, b, acc[cf], 0, 0, 0);
            }
        }
    }
#pragma unroll
    for (int cf = 0; cf < 4; ++cf) {
        int ctl = blockIdx.y * 4 + cf;
        if (ctl >= zct) continue;
        int colc = ctl * 16 + lr;
#pragma unroll
        for (int r = 0; r < 4; ++r) {
            int rowc = m0 + lg * 4 + r;
            if (rowc < M) Z[(size_t)rowc * zld + colc] = f2h(acc[cf][r]);
        }
    }
}

// phase A: block stages NODES col-nodes' z rows (125*CH fp16 each) into LDS,
// then each CH-lane group processes edges (col-sorted) -> msg fp16, plain store.
template<int CH, int NODES>
__global__ __launch_bounds__(256) void msgA_kernel(
        const unsigned short* __restrict__ z,
        const float* __restrict__ basis, const unsigned char* __restrict__ idxb,
        const int* __restrict__ cstart, const int* __restrict__ colS,
        unsigned short* __restrict__ msg, int msgld, int coff, int N, int E) {
    const int ROW = 125 * CH;
    __shared__ unsigned short lds[NODES * 125 * CH];
    int n0 = blockIdx.x * NODES;
    if (n0 >= N) return;
    int rows = N - n0; if (rows > NODES) rows = NODES;
    int nv4 = rows * ROW / 8;
    const uint4* src = (const uint4*)(z + (size_t)n0 * ROW);
    uint4* dst = (uint4*)lds;
    for (int i = threadIdx.x; i < nv4; i += 256) dst[i] = src[i];
    __syncthreads();
    int estart = cstart[n0];
    int eend = (n0 + NODES < N) ? cstart[n0 + NODES] : E;
    const int NG = 256 / CH;
    int g = threadIdx.x / CH, l = threadIdx.x % CH;
    for (int j = estart + g; j < eend; j += NG) {
        int node = colS[j] - n0;
        const float4* bp = (const float4*)(basis + (size_t)j * 8);
        float4 b0 = bp[0], b1v = bp[1];
        const uchar4* ip = (const uchar4*)(idxb + (size_t)j * 8);
        uchar4 i0 = ip[0], i1 = ip[1];
        const unsigned short* zr = lds + node * ROW;
        float m = b0.x * h2f(zr[i0.x * CH + l]) + b0.y * h2f(zr[i0.y * CH + l])
                + b0.z * h2f(zr[i0.z * CH + l]) + b0.w * h2f(zr[i0.w * CH + l])
                + b1v.x * h2f(zr[i1.x * CH + l]) + b1v.y * h2f(zr[i1.y * CH + l])
                + b1v.z * h2f(zr[i1.z * CH + l]) + b1v.w * h2f(zr[i1.w * CH + l]);
        msg[(size_t)j * msgld + coff + l] = f2h(m);
    }
}

// phase B conv1 (fused): W1 (125x64 fp32, 32KB) in LDS; wave per row-node;
// msg computed on the fly from basis/idx; fused mean+bias+elu -> h1 bf16.
__global__ __launch_bounds__(256) void phaseB1_kernel(
        const float* __restrict__ W1, const float* __restrict__ basis,
        const unsigned char* __restrict__ idxb, const int* __restrict__ perm,
        const int* __restrict__ rowStart, const int* __restrict__ histR,
        const float* __restrict__ b1, unsigned short* __restrict__ h1b, int N) {
    __shared__ float w[125 * 64];
    for (int i = threadIdx.x; i < 125 * 64; i += 256) w[i] = W1[i];
    __syncthreads();
    int n = blockIdx.x * 4 + (threadIdx.x >> 6);
    if (n >= N) return;
    int l = threadIdx.x & 63;
    int s0 = rowStart[n], cnt = histR[n];
    float a = 0.0f;
    for (int base = 0; base < cnt; base += 64) {
        int c = cnt - base < 64 ? cnt - base : 64;
        int pv = (l < c) ? perm[s0 + base + l] : 0;
        for (int i = 0; i < c; ++i) {
            int slot = __shfl(pv, i);
            const float4* bp = (const float4*)(basis + (size_t)slot * 8);
            float4 b0 = bp[0], b1v = bp[1];
            const uchar4* ip = (const uchar4*)(idxb + (size_t)slot * 8);
            uchar4 i0 = ip[0], i1 = ip[1];
            a += b0.x * w[i0.x * 64 + l] + b0.y * w[i0.y * 64 + l]
               + b0.z * w[i0.z * 64 + l] + b0.w * w[i0.w * 64 + l]
               + b1v.x * w[i1.x * 64 + l] + b1v.y * w[i1.y * 64 + l]
               + b1v.z * w[i1.z * 64 + l] + b1v.w * w[i1.w * 64 + l];
        }
    }
    float v = a / fmaxf((float)cnt, 1.0f) + b1[l];
    v = (v > 0.0f) ? v : (expf(v) - 1.0f);
    h1b[(size_t)n * 64 + l] = f2b(v);
}

// phase B, 64ch: wave per row-node; msg fp16; fused mean+bias+elu -> h2 fp32.
__global__ __launch_bounds__(256) void phaseB64_kernel(
        const unsigned short* __restrict__ msg, const int* __restrict__ perm,
        const int* __restrict__ rowStart, const int* __restrict__ histR,
        const float* __restrict__ bias, float* __restrict__ outF, int N) {
    int n = blockIdx.x * 4 + (threadIdx.x >> 6);
    if (n >= N) return;
    int l = threadIdx.x & 63;
    int s0 = rowStart[n], cnt = histR[n];
    float a = 0.0f;
    for (int base = 0; base < cnt; base += 64) {
        int c = cnt - base < 64 ? cnt - base : 64;
        int pv = (l < c) ? perm[s0 + base + l] : 0;
        for (int i = 0; i < c; ++i) {
            int slot = __shfl(pv, i);
            a += h2f(msg[(size_t)slot * 64 + l]);
        }
    }
    float v = a / fmaxf((float)cnt, 1.0f) + bias[l];
    v = (v > 0.0f) ? v : (expf(v) - 1.0f);
    outF[(size_t)n * 64 + l] = v;
}

// phase B, 32ch: half-wave per row-node; fused mean+bias -> out fp32.
__global__ __launch_bounds__(256) void phaseB32_kernel(
        const unsigned short* __restrict__ msg, const int* __restrict__ perm,
        const int* __restrict__ rowStart, const int* __restrict__ histR,
        const float* __restrict__ bias, float* __restrict__ out, int N) {
    int n = blockIdx.x * 8 + (threadIdx.x >> 5);
    if (n >= N) return;
    int l = threadIdx.x & 31;
    int s0 = rowStart[n], cnt = histR[n];
    float a = 0.0f;
    for (int base = 0; base < cnt; base += 32) {
        int c = cnt - base < 32 ? cnt - base : 32;
        int pv = (l < c) ? perm[s0 + base + l] : 0;
        for (int i = 0; i < c; ++i) {
            int slot = __shfl(pv, i, 32);
            a += h2f(msg[(size_t)slot * 32 + l]);
        }
    }
    out[(size_t)n * 32 + l] = a / fmaxf((float)cnt, 1.0f) + bias[l];
}

// stn3 + stn4 per node
__global__ __launch_bounds__(64) void stn34_kernel(
        const float* __restrict__ h2, const float* __restrict__ w3,
        const float* __restrict__ b3, const float* __restrict__ w4,
        const float* __restrict__ b4, float* __restrict__ t, int N) {
    int n = blockIdx.x;
    int o = threadIdx.x;
    __shared__ float sh[64];
    __shared__ float sh3[64];
    sh[o] = h2[n * 64 + o];
    __syncthreads();
    float v = b3[o];
#pragma unroll
    for (int i = 0; i < 64; ++i) v += sh[i] * w3[i * 64 + o];
    v = (v > 0.0f) ? v : (expf(v) - 1.0f);
    sh3[o] = v;
    __syncthreads();
    if (o < 3) {
        float tv = b4[o];
#pragma unroll
        for (int i = 0; i < 64; ++i) tv += sh3[i] * w4[i * 3 + o];
        t[n * 3 + o] = tv;
    }
}

// ---- minimal fallback (only if ws is tiny; R1-style direct, correct) ----
__global__ __launch_bounds__(256) void conv1_at_kernel(
        const float* __restrict__ basis, const unsigned char* __restrict__ idxb,
        const int* __restrict__ row, const float* __restrict__ W1,
        float* __restrict__ acc, int E) {
    int j = blockIdx.x * 4 + (threadIdx.x >> 6);
    if (j >= E) return;
    int l = threadIdx.x & 63;
    float m = 0.0f;
#pragma unroll
    for (int s = 0; s < 8; ++s) m += basis[(size_t)j * 8 + s] * W1[idxb[(size_t)j * 8 + s] * 64 + l];
    atomicAdd(&acc[(size_t)row[j] * 64 + l], m);
}

__global__ __launch_bounds__(256) void conv2f_kernel(
        const float* __restrict__ h1, const float* __restrict__ basis,
        const unsigned char* __restrict__ idxb, const int* __restrict__ row,
        const int* __restrict__ col, const float* __restrict__ W2,
        float* __restrict__ acc, int E) {
    int wid = threadIdx.x >> 6;
    int lane = threadIdx.x & 63;
    int e = blockIdx.x * 4 + wid;
    __shared__ float sh[4][64];
    bool active = (e < E);
    int c = active ? col[e] : 0;
    if (active) sh[wid][lane] = h1[(size_t)c * 64 + lane];
    __syncthreads();
    if (!active) return;
    float m = 0.0f;
#pragma unroll
    for (int s = 0; s < 8; ++s) {
        const float* Wk = W2 + (size_t)idxb[(size_t)e * 8 + s] * 4096;
        float ms = 0.0f;
#pragma unroll
        for (int i = 0; i < 64; ++i) ms += sh[wid][i] * Wk[i * 64 + lane];
        m += basis[(size_t)e * 8 + s] * ms;
    }
    atomicAdd(&acc[(size_t)row[e] * 64 + lane], m);
}

__global__ __launch_bounds__(256) void conv3f_kernel(
        const float* __restrict__ x, const float* __restrict__ basis,
        const unsigned char* __restrict__ idxb, const int* __restrict__ row,
        const int* __restrict__ col, const float* __restrict__ Wc,
        float* __restrict__ acc, int E) {
    int wid = threadIdx.x >> 6;
    int lane = threadIdx.x & 63;
    int e = blockIdx.x * 4 + wid;
    __shared__ float sx[4][32];
    bool active = (e < E);
    int c = active ? col[e] : 0;
    if (active && lane < 32) sx[wid][lane] = x[(size_t)c * 32 + lane];
    __syncthreads();
    int half = lane >> 5;
    int o = lane & 31;
    float m = 0.0f;
    if (active) {
#pragma unroll
        for (int s2 = 0; s2 < 4; ++s2) {
            int s = half * 4 + s2;
            const float* Wk = Wc + (size_t)idxb[(size_t)e * 8 + s] * 1024;
            float ms = 0.0f;
#pragma unroll
            for (int i = 0; i < 32; ++i) ms += sx[wid][i] * Wk[i * 32 + o];
            m += basis[(size_t)e * 8 + s] * ms;
        }
    }
    m += __shfl_xor(m, 32);
    if (active && lane < 32) atomicAdd(&acc[(size_t)row[e] * 32 + o], m);
}

__global__ void finalize_kernel(const float* __restrict__ acc, const int* __restrict__ histR,
                                const float* __restrict__ bias, float* __restrict__ outF,
                                unsigned short* __restrict__ outB,
                                int N, int F, int do_elu) {
    int t = blockIdx.x * blockDim.x + threadIdx.x;
    if (t >= N * F) return;
    int n = t / F, o = t % F;
    float v = acc[t] / fmaxf((float)histR[n], 1.0f) + bias[o];
    if (do_elu) v = (v > 0.0f) ? v : (expf(v) - 1.0f);
    if (outF) outF[t] = v;
    if (outB) outB[t] = f2b(v);
}

extern "C" void kernel_launch(void* const* d_in, const int* in_sizes, int n_in,
                              void* d_out, int out_size, void* d_ws, size_t ws_size,
                              hipStream_t stream) {
    const float* x      = (const float*)d_in[0];
    const int*   ei     = (const int*)d_in[1];
    const float* pseudo = (const float*)d_in[2];
    const float* w1     = (const float*)d_in[3];
    const float* b1     = (const float*)d_in[4];
    const float* w2     = (const float*)d_in[5];
    const float* b2     = (const float*)d_in[6];
    const float* w3     = (const float*)d_in[7];
    const float* b3     = (const float*)d_in[8];
    const float* w4     = (const float*)d_in[9];
    const float* b4     = (const float*)d_in[10];
    const float* wc     = (const float*)d_in[11];
    const float* cb     = (const float*)d_in[12];
    float* out = (float*)d_out;

    const int N = in_sizes[0] / 32;
    const int E = in_sizes[1] / 2;
    const int* row = ei;
    const int* col = ei + E;
    const int KC = 125;

    char* p = (char*)d_ws;
    // zeroed: histograms
    int* histR = (int*)p; p += (size_t)N * sizeof(int);
    int* histC = (int*)p; p += (size_t)N * sizeof(int);
    size_t zero_bytes = (size_t)(p - (char*)d_ws);
    // non-zeroed
    int* cstart   = (int*)p; p += (size_t)N * sizeof(int);
    int* cursorC  = (int*)p; p += (size_t)N * sizeof(int);
    int* rowStart = (int*)p; p += (size_t)N * sizeof(int);
    int* cursorR  = (int*)p; p += (size_t)N * sizeof(int);
    int* jpos = (int*)p; p += (size_t)E * sizeof(int);
    int* colS = (int*)p; p += (size_t)E * sizeof(int);
    int* perm = (int*)p; p += (size_t)E * sizeof(int);
    float* h2 = (float*)p; p += (size_t)N * 64 * sizeof(float);
    float* tt = (float*)p; p += (size_t)N * 3 * sizeof(float);
    float* basis = (float*)p; p += (size_t)E * 8 * sizeof(float);
    unsigned char* idxb = (unsigned char*)p; p += (size_t)E * 8;
    unsigned short* h1b = (unsigned short*)p; p += (size_t)N * 64 * sizeof(short);
    unsigned short* xb  = (unsigned short*)p; p += (size_t)N * 32 * sizeof(short);
    unsigned short* BF2 = (unsigned short*)p; p += (size_t)KC * 64 * 64 * sizeof(short);
    unsigned short* BF3 = (unsigned short*)p; p += (size_t)KC * 32 * 32 * sizeof(short);
    unsigned short* msg = (unsigned short*)p; p += (size_t)E * 64 * sizeof(short);
    size_t fixed = (size_t)(p - (char*)d_ws);
    size_t zcap = (ws_size > fixed) ? (ws_size - fixed) : 0;
    unsigned short* zbuf = (unsigned short*)p;

    const size_t MB = 1024 * 1024;
    const size_t z_half = (size_t)N * KC * 32 * sizeof(short);   // 160MB
    const size_t z_quar = (size_t)N * KC * 16 * sizeof(short);   // 80MB
    int mode = (zcap >= z_half) ? 2 : (zcap >= z_quar ? 4 : 0);  // H2 split count

    hipMemsetAsync(d_ws, 0, zero_bytes, stream);
    hist_kernel<<<(E + 255) / 256, 256, 0, stream>>>(row, col, histR, histC, E);

    const int MT = (N + 63) / 64;

    if (mode) {
        const int H2 = mode;            // conv2 channel splits
        const int CH2 = 64 / H2;        // 32 or 16
        const int H3 = (mode == 2) ? 1 : 2;
        const int CH3 = 32 / H3;

        pack_w_kernel<<<(KC * 64 * 64 + 255) / 256, 256, 0, stream>>>(w2, BF2, KC, 64, 64, 2, CH2);
        pack_w_kernel<<<(KC * 32 * 32 + 255) / 256, 256, 0, stream>>>(wc, BF3, KC, 32, 32, 1, CH3);
        castbf_kernel<<<(N * 32 + 255) / 256, 256, 0, stream>>>(x, xb, N * 32);

        scan_kernel<<<1, 1024, 0, stream>>>(histC, cstart, cursorC, N);
        scan_kernel<<<1, 1024, 0, stream>>>(histR, rowStart, cursorR, N);
        scatter_kernel<<<(E + 255) / 256, 256, 0, stream>>>(row, col, cursorC, cursorR,
                                                            jpos, colS, perm, E);
        basis1_kernel<<<(E + 255) / 256, 256, 0, stream>>>(pseudo, jpos, basis, idxb, E);

        // conv1: fully fused phase B
        phaseB1_kernel<<<(N + 3) / 4, 256, 0, stream>>>(w1, basis, idxb, perm, rowStart,
                                                        histR, b1, h1b, N);
        // conv2: channel-split z
        for (int s = 0; s < H2; ++s) {
            int zct = KC * CH2 / 16;
            dim3 g(MT, (zct + 3) / 4);
            zgemm_kernel<2><<<g, 256, 0, stream>>>(h1b, N, BF2, zbuf, KC * CH2, s * zct, zct);
            if (CH2 == 32)
                msgA_kernel<32, 4><<<(N + 3) / 4, 256, 0, stream>>>(
                    zbuf, basis, idxb, cstart, colS, msg, 64, s * 32, N, E);
            else
                msgA_kernel<16, 8><<<(N + 7) / 8, 256, 0, stream>>>(
                    zbuf, basis, idxb, cstart, colS, msg, 64, s * 16, N, E);
        }
        phaseB64_kernel<<<(N + 3) / 4, 256, 0, stream>>>(msg, perm, rowStart, histR, b2, h2, N);

        stn34_kernel<<<N, 64, 0, stream>>>(h2, w3, b3, w4, b4, tt, N);
        basis2_kernel<<<(E + 255) / 256, 256, 0, stream>>>(pseudo, tt, row, col, jpos,
                                                           basis, idxb, E);
        // conv3
        for (int s = 0; s < H3; ++s) {
            int zct = KC * CH3 / 16;
            dim3 g(MT, (zct + 3) / 4);
            zgemm_kernel<1><<<g, 256, 0, stream>>>(xb, N, BF3, zbuf, KC * CH3, s * zct, zct);
            if (CH3 == 32)
                msgA_kernel<32, 4><<<(N + 3) / 4, 256, 0, stream>>>(
                    zbuf, basis, idxb, cstart, colS, msg, 32, 0, N, E);
            else
                msgA_kernel<16, 8><<<(N + 7) / 8, 256, 0, stream>>>(
                    zbuf, basis, idxb, cstart, colS, msg, 32, s * 16, N, E);
        }
        phaseB32_kernel<<<(N + 7) / 8, 256, 0, stream>>>(msg, perm, rowStart, histR, cb, out, N);
    } else {
        // tiny-ws fallback: direct convs with atomics (correct, slow)
        float* deg_unused = nullptr; (void)deg_unused;
        float* acc1 = (float*)msg;                 // alias into msg region
        float* acc2 = acc1 + (size_t)N * 64;
        float* acc3 = acc2 + (size_t)N * 64;
        float* h1f  = acc3 + (size_t)N * 32;
        size_t acc_bytes = (size_t)N * (64 + 64 + 32) * sizeof(float);
        hipMemsetAsync((void*)acc1, 0, acc_bytes, stream);

        basis1_kernel<<<(E + 255) / 256, 256, 0, stream>>>(pseudo, nullptr, basis, idxb, E);
        conv1_at_kernel<<<(E + 3) / 4, 256, 0, stream>>>(basis, idxb, row, w1, acc1, E);
        finalize_kernel<<<(N * 64 + 255) / 256, 256, 0, stream>>>(acc1, histR, b1, h1f, nullptr, N, 64, 1);
        conv2f_kernel<<<(E + 3) / 4, 256, 0, stream>>>(h1f, basis, idxb, row, col, w2, acc2, E);
        finalize_kernel<<<(N * 64 + 255) / 256, 256, 0, stream>>>(acc2, histR, b2, h2, nullptr, N, 64, 1);
        stn34_kernel<<<N, 64, 0, stream>>>(h2, w3, b3, w4, b4, tt, N);
        basis2_kernel<<<(E + 255) / 256, 256, 0, stream>>>(pseudo, tt, row, col, nullptr, basis, idxb, E);
        conv3f_kernel<<<(E + 3) / 4, 256, 0, stream>>>(x, basis, idxb, row, col, wc, acc3, E);
        finalize_kernel<<<(N * 32 + 255) / 256, 256, 0, stream>>>(acc3, histR, cb, out, nullptr, N, 32, 0);
    }
    (void)MB;
}

// Round 6
// 558.995 us; speedup vs baseline: 1.4551x; 1.0025x over previous
//
#include <hip/hip_runtime.h>
#include <hip/hip_bf16.h>
#include <math.h>

// InvGraphConv: SplineCNN block on MI355X.
// N=20000, E=320000, D=3, KS=5 -> K=125, S=8, Fin=Fout=32, hidden=64.
//
// R6: R5 structure (atomic-free dual-sort message passing, channel-split z)
// with rewritten zgemm: 128 rows/block (2 row-frags per wave share B frags)
// + LDS-bounce epilogue for fully coalesced uint4 z stores.

typedef short  s16x8 __attribute__((ext_vector_type(8)));
typedef float  f32x4 __attribute__((ext_vector_type(4)));

__device__ __forceinline__ unsigned short f2b(float f) {
    __hip_bfloat16 h = __float2bfloat16(f);
    return __builtin_bit_cast(unsigned short, h);
}
__device__ __forceinline__ unsigned short f2h(float f) {
    _Float16 h = (_Float16)f;
    return __builtin_bit_cast(unsigned short, h);
}
__device__ __forceinline__ float h2f(unsigned short u) {
    _Float16 h = __builtin_bit_cast(_Float16, u);
    return (float)h;
}

__device__ __forceinline__ void spline8(const float u0, const float u1, const float u2,
                                        float* __restrict__ b, int* __restrict__ id) {
    const float u[3] = {u0, u1, u2};
    const int strides[3] = {25, 5, 1};
    float fr[3];
    int   i0[3];
#pragma unroll
    for (int d = 0; d < 3; ++d) {
        float p = u[d] * 4.0f;
        float f = floorf(p);
        f = fminf(fmaxf(f, 0.0f), 3.0f);
        i0[d] = (int)f;
        fr[d] = p - f;
    }
#pragma unroll
    for (int s = 0; s < 8; ++s) {
        float bb = 1.0f;
        int   ii = 0;
#pragma unroll
        for (int d = 0; d < 3; ++d) {
            int c = (s >> d) & 1;
            bb *= c ? fr[d] : (1.0f - fr[d]);
            ii += (i0[d] + c) * strides[d];
        }
        b[s] = bb;
        id[s] = ii;
    }
}

__global__ void hist_kernel(const int* __restrict__ row, const int* __restrict__ col,
                            int* __restrict__ histR, int* __restrict__ histC, int E) {
    int e = blockIdx.x * blockDim.x + threadIdx.x;
    if (e >= E) return;
    atomicAdd(&histR[row[e]], 1);
    atomicAdd(&histC[col[e]], 1);
}

// single-block exclusive scan of hist[N] -> out1 (and optional copy out2)
__global__ __launch_bounds__(1024) void scan_kernel(const int* __restrict__ hist,
                                                    int* __restrict__ out1,
                                                    int* __restrict__ out2, int N) {
    __shared__ int wsum[16];
    __shared__ int carry;
    int t = threadIdx.x, lane = t & 63, w = t >> 6;
    if (t == 0) carry = 0;
    __syncthreads();
    for (int base = 0; base < N; base += 1024) {
        int i = base + t;
        int v = (i < N) ? hist[i] : 0;
        int sc = v;
#pragma unroll
        for (int off = 1; off < 64; off <<= 1) {
            int u = __shfl_up(sc, off);
            if (lane >= off) sc += u;
        }
        if (lane == 63) wsum[w] = sc;
        __syncthreads();
        if (w == 0 && lane < 16) {
            int s = wsum[lane];
#pragma unroll
            for (int off = 1; off < 16; off <<= 1) {
                int u = __shfl_up(s, off);
                if (lane >= off) s += u;
            }
            wsum[lane] = s;
        }
        __syncthreads();
        int woff = (w > 0 ? wsum[w - 1] : 0) + carry;
        int excl = woff + sc - v;
        if (i < N) {
            out1[i] = excl;
            if (out2) out2[i] = excl;
        }
        __syncthreads();
        if (t == 0) carry += wsum[15];
        __syncthreads();
    }
}

// dual scatter: jc = col-sorted slot, jr = row-sorted slot; perm[jr]=jc.
__global__ void scatter_kernel(const int* __restrict__ row, const int* __restrict__ col,
                               int* __restrict__ cursorC, int* __restrict__ cursorR,
                               int* __restrict__ jpos, int* __restrict__ colS,
                               int* __restrict__ perm, int E) {
    int e = blockIdx.x * blockDim.x + threadIdx.x;
    if (e >= E) return;
    int c = col[e], r = row[e];
    int jc = atomicAdd(&cursorC[c], 1);
    int jr = atomicAdd(&cursorR[r], 1);
    jpos[e] = jc;
    colS[jc] = c;
    perm[jr] = jc;
}

__global__ void basis1_kernel(const float* __restrict__ pseudo, const int* __restrict__ jpos,
                              float* __restrict__ basis, unsigned char* __restrict__ idxb, int E) {
    int e = blockIdx.x * blockDim.x + threadIdx.x;
    if (e >= E) return;
    float b[8]; int id[8];
    spline8(pseudo[e * 3 + 0], pseudo[e * 3 + 1], pseudo[e * 3 + 2], b, id);
    int j = jpos ? jpos[e] : e;
#pragma unroll
    for (int s = 0; s < 8; ++s) { basis[(size_t)j * 8 + s] = b[s]; idxb[(size_t)j * 8 + s] = (unsigned char)id[s]; }
}

__global__ void basis2_kernel(const float* __restrict__ pseudo, const float* __restrict__ t,
                              const int* __restrict__ row, const int* __restrict__ col,
                              const int* __restrict__ jpos,
                              float* __restrict__ basis, unsigned char* __restrict__ idxb, int E) {
    int e = blockIdx.x * blockDim.x + threadIdx.x;
    if (e >= E) return;
    int r = row[e], c = col[e];
    float u[3];
#pragma unroll
    for (int d = 0; d < 3; ++d) {
        float v = pseudo[e * 3 + d] + t[c * 3 + d] - t[r * 3 + d];
        u[d] = fminf(fmaxf(v, 0.0f), 1.0f);
    }
    float b[8]; int id[8];
    spline8(u[0], u[1], u[2], b, id);
    int j = jpos ? jpos[e] : e;
#pragma unroll
    for (int s = 0; s < 8; ++s) { basis[(size_t)j * 8 + s] = b[s]; idxb[(size_t)j * 8 + s] = (unsigned char)id[s]; }
}

__global__ void castbf_kernel(const float* __restrict__ in, unsigned short* __restrict__ out,
                              int n) {
    int t = blockIdx.x * blockDim.x + threadIdx.x;
    if (t < n) out[t] = f2b(in[t]);
}

// Pack W [Kc][Fin][Fout] fp32 -> MFMA B-fragments bf16, channel-split order:
// global col c' = (o/CH)*(Kc*CH) + k*CH + o%CH.
__global__ void pack_w_kernel(const float* __restrict__ W, unsigned short* __restrict__ BF,
                              int Kc, int Fin, int Fout, int ksteps, int CH) {
    int t = blockIdx.x * blockDim.x + threadIdx.x;
    int total = Kc * Fout * Fin;
    if (t >= total) return;
    int c = t / Fin;
    int i = t % Fin;
    int kk = c / Fout, o = c % Fout;
    int split = o / CH;
    int cp = split * (Kc * CH) + kk * CH + (o % CH);
    int ct = cp >> 4, lr = cp & 15;
    int step = i >> 5, rem = i & 31, lg = rem >> 3, jj = rem & 7;
    size_t dst = ((((size_t)ct * ksteps + step) * 4 + lg) * 16 + lr) * 8 + jj;
    BF[dst] = f2b(W[((size_t)kk * Fin + i) * Fout + o]);
}

// z = A @ B via mfma_f32_16x16x32_bf16 -> fp16 Z [M][zld].
// 128 rows/block (4 waves x 2 row-frags), 64 cols/block (4 col-frags).
// Epilogue bounces through LDS for fully coalesced uint4 stores.
template<int KSTEPS>
__global__ __launch_bounds__(256) void zgemm_kernel(
        const unsigned short* __restrict__ A, int M,
        const unsigned short* __restrict__ BF,
        unsigned short* __restrict__ Z, int zld, int ct0, int zct) {
    __shared__ unsigned short ztile[128 * 64];  // 16 KB
    int w = threadIdx.x >> 6, l = threadIdx.x & 63;
    int lr = l & 15, lg = l >> 4;
    int base = blockIdx.x * 128;
    const int KD = KSTEPS * 32;
    f32x4 acc0[4], acc1[4];
#pragma unroll
    for (int cf = 0; cf < 4; ++cf) { acc0[cf] = (f32x4){0,0,0,0}; acc1[cf] = (f32x4){0,0,0,0}; }
    int arow0 = base + w * 16 + lr;      if (arow0 > M - 1) arow0 = M - 1;
    int arow1 = base + 64 + w * 16 + lr; if (arow1 > M - 1) arow1 = M - 1;
#pragma unroll
    for (int step = 0; step < KSTEPS; ++step) {
        s16x8 a0 = *(const s16x8*)(A + (size_t)arow0 * KD + step * 32 + lg * 8);
        s16x8 a1 = *(const s16x8*)(A + (size_t)arow1 * KD + step * 32 + lg * 8);
#pragma unroll
        for (int cf = 0; cf < 4; ++cf) {
            int ctl = blockIdx.y * 4 + cf;
            if (ctl < zct) {
                int ctg = ct0 + ctl;
                const unsigned short* bp =
                    BF + ((((size_t)ctg * KSTEPS + step) * 4 + lg) * 16 + lr) * 8;
                s16x8 b = *(const s16x8*)bp;
                acc0[cf] = __builtin_amdgcn_mfma_f32_16x16x32_bf16(a0, b, acc0[cf], 0, 0, 0);
                acc1[cf] = __builtin_amdgcn_mfma_f32_16x16x32_bf16(a1, b, acc1[cf], 0, 0, 0);
            }
        }
    }
    // acc -> LDS fp16 tile
#pragma unroll
    for (int cf = 0; cf < 4; ++cf) {
        int colL = cf * 16 + lr;
#pragma unroll
        for (int r = 0; r < 4; ++r) {
            int rl0 = w * 16 + lg * 4 + r;
            ztile[rl0 * 64 + colL] = f2h(acc0[cf][r]);
            ztile[(rl0 + 64) * 64 + colL] = f2h(acc1[cf][r]);
        }
    }
    __syncthreads();
    // coalesced copy out: 128 rows x 64 fp16 = 1024 uint4
    int rows_in = M - base; if (rows_in > 128) rows_in = 128;
    int valid_cols = (zct - blockIdx.y * 4) * 16; if (valid_cols > 64) valid_cols = 64;
    int bcol = blockIdx.y * 64;
    for (int i = threadIdx.x; i < 128 * 8; i += 256) {
        int rl = i >> 3, cq = (i & 7) * 8;
        if (rl < rows_in && cq < valid_cols) {
            uint4 v = ((const uint4*)ztile)[i];
            *(uint4*)(Z + (size_t)(base + rl) * zld + bcol + cq) = v;
        }
    }
}

// phase A: block stages NODES col-nodes' z rows (125*CH fp16 each) into LDS,
// then each CH-lane group processes edges (col-sorted) -> msg fp16, plain store.
template<int CH, int NODES>
__global__ __launch_bounds__(256) void msgA_kernel(
        const unsigned short* __restrict__ z,
        const float* __restrict__ basis, const unsigned char* __restrict__ idxb,
        const int* __restrict__ cstart, const int* __restrict__ colS,
        unsigned short* __restrict__ msg, int msgld, int coff, int N, int E) {
    const int ROW = 125 * CH;
    __shared__ unsigned short lds[NODES * 125 * CH];
    int n0 = blockIdx.x * NODES;
    if (n0 >= N) return;
    int rows = N - n0; if (rows > NODES) rows = NODES;
    int nv4 = rows * ROW / 8;
    const uint4* src = (const uint4*)(z + (size_t)n0 * ROW);
    uint4* dst = (uint4*)lds;
    for (int i = threadIdx.x; i < nv4; i += 256) dst[i] = src[i];
    __syncthreads();
    int estart = cstart[n0];
    int eend = (n0 + NODES < N) ? cstart[n0 + NODES] : E;
    const int NG = 256 / CH;
    int g = threadIdx.x / CH, l = threadIdx.x % CH;
    for (int j = estart + g; j < eend; j += NG) {
        int node = colS[j] - n0;
        const float4* bp = (const float4*)(basis + (size_t)j * 8);
        float4 b0 = bp[0], b1v = bp[1];
        const uchar4* ip = (const uchar4*)(idxb + (size_t)j * 8);
        uchar4 i0 = ip[0], i1 = ip[1];
        const unsigned short* zr = lds + node * ROW;
        float m = b0.x * h2f(zr[i0.x * CH + l]) + b0.y * h2f(zr[i0.y * CH + l])
                + b0.z * h2f(zr[i0.z * CH + l]) + b0.w * h2f(zr[i0.w * CH + l])
                + b1v.x * h2f(zr[i1.x * CH + l]) + b1v.y * h2f(zr[i1.y * CH + l])
                + b1v.z * h2f(zr[i1.z * CH + l]) + b1v.w * h2f(zr[i1.w * CH + l]);
        msg[(size_t)j * msgld + coff + l] = f2h(m);
    }
}

// phase B conv1 (fused): W1 (125x64 fp32, 32KB) in LDS; wave per row-node.
__global__ __launch_bounds__(256) void phaseB1_kernel(
        const float* __restrict__ W1, const float* __restrict__ basis,
        const unsigned char* __restrict__ idxb, const int* __restrict__ perm,
        const int* __restrict__ rowStart, const int* __restrict__ histR,
        const float* __restrict__ b1, unsigned short* __restrict__ h1b, int N) {
    __shared__ float w[125 * 64];
    for (int i = threadIdx.x; i < 125 * 64; i += 256) w[i] = W1[i];
    __syncthreads();
    int n = blockIdx.x * 4 + (threadIdx.x >> 6);
    if (n >= N) return;
    int l = threadIdx.x & 63;
    int s0 = rowStart[n], cnt = histR[n];
    float a = 0.0f;
    for (int base = 0; base < cnt; base += 64) {
        int c = cnt - base < 64 ? cnt - base : 64;
        int pv = (l < c) ? perm[s0 + base + l] : 0;
        for (int i = 0; i < c; ++i) {
            int slot = __shfl(pv, i);
            const float4* bp = (const float4*)(basis + (size_t)slot * 8);
            float4 b0 = bp[0], b1v = bp[1];
            const uchar4* ip = (const uchar4*)(idxb + (size_t)slot * 8);
            uchar4 i0 = ip[0], i1 = ip[1];
            a += b0.x * w[i0.x * 64 + l] + b0.y * w[i0.y * 64 + l]
               + b0.z * w[i0.z * 64 + l] + b0.w * w[i0.w * 64 + l]
               + b1v.x * w[i1.x * 64 + l] + b1v.y * w[i1.y * 64 + l]
               + b1v.z * w[i1.z * 64 + l] + b1v.w * w[i1.w * 64 + l];
        }
    }
    float v = a / fmaxf((float)cnt, 1.0f) + b1[l];
    v = (v > 0.0f) ? v : (expf(v) - 1.0f);
    h1b[(size_t)n * 64 + l] = f2b(v);
}

// phase B, 64ch: wave per row-node; fused mean+bias+elu -> h2 fp32.
__global__ __launch_bounds__(256) void phaseB64_kernel(
        const unsigned short* __restrict__ msg, const int* __restrict__ perm,
        const int* __restrict__ rowStart, const int* __restrict__ histR,
        const float* __restrict__ bias, float* __restrict__ outF, int N) {
    int n = blockIdx.x * 4 + (threadIdx.x >> 6);
    if (n >= N) return;
    int l = threadIdx.x & 63;
    int s0 = rowStart[n], cnt = histR[n];
    float a = 0.0f;
    for (int base = 0; base < cnt; base += 64) {
        int c = cnt - base < 64 ? cnt - base : 64;
        int pv = (l < c) ? perm[s0 + base + l] : 0;
        for (int i = 0; i < c; ++i) {
            int slot = __shfl(pv, i);
            a += h2f(msg[(size_t)slot * 64 + l]);
        }
    }
    float v = a / fmaxf((float)cnt, 1.0f) + bias[l];
    v = (v > 0.0f) ? v : (expf(v) - 1.0f);
    outF[(size_t)n * 64 + l] = v;
}

// phase B, 32ch: half-wave per row-node; fused mean+bias -> out fp32.
__global__ __launch_bounds__(256) void phaseB32_kernel(
        const unsigned short* __restrict__ msg, const int* __restrict__ perm,
        const int* __restrict__ rowStart, const int* __restrict__ histR,
        const float* __restrict__ bias, float* __restrict__ out, int N) {
    int n = blockIdx.x * 8 + (threadIdx.x >> 5);
    if (n >= N) return;
    int l = threadIdx.x & 31;
    int s0 = rowStart[n], cnt = histR[n];
    float a = 0.0f;
    for (int base = 0; base < cnt; base += 32) {
        int c = cnt - base < 32 ? cnt - base : 32;
        int pv = (l < c) ? perm[s0 + base + l] : 0;
        for (int i = 0; i < c; ++i) {
            int slot = __shfl(pv, i, 32);
            a += h2f(msg[(size_t)slot * 32 + l]);
        }
    }
    out[(size_t)n * 32 + l] = a / fmaxf((float)cnt, 1.0f) + bias[l];
}

// stn3 + stn4 per node
__global__ __launch_bounds__(64) void stn34_kernel(
        const float* __restrict__ h2, const float* __restrict__ w3,
        const float* __restrict__ b3, const float* __restrict__ w4,
        const float* __restrict__ b4, float* __restrict__ t, int N) {
    int n = blockIdx.x;
    int o = threadIdx.x;
    __shared__ float sh[64];
    __shared__ float sh3[64];
    sh[o] = h2[n * 64 + o];
    __syncthreads();
    float v = b3[o];
#pragma unroll
    for (int i = 0; i < 64; ++i) v += sh[i] * w3[i * 64 + o];
    v = (v > 0.0f) ? v : (expf(v) - 1.0f);
    sh3[o] = v;
    __syncthreads();
    if (o < 3) {
        float tv = b4[o];
#pragma unroll
        for (int i = 0; i < 64; ++i) tv += sh3[i] * w4[i * 3 + o];
        t[n * 3 + o] = tv;
    }
}

// ---- minimal fallback (only if ws is tiny; direct, correct) ----
__global__ __launch_bounds__(256) void conv1_at_kernel(
        const float* __restrict__ basis, const unsigned char* __restrict__ idxb,
        const int* __restrict__ row, const float* __restrict__ W1,
        float* __restrict__ acc, int E) {
    int j = blockIdx.x * 4 + (threadIdx.x >> 6);
    if (j >= E) return;
    int l = threadIdx.x & 63;
    float m = 0.0f;
#pragma unroll
    for (int s = 0; s < 8; ++s) m += basis[(size_t)j * 8 + s] * W1[idxb[(size_t)j * 8 + s] * 64 + l];
    atomicAdd(&acc[(size_t)row[j] * 64 + l], m);
}

__global__ __launch_bounds__(256) void conv2f_kernel(
        const float* __restrict__ h1, const float* __restrict__ basis,
        const unsigned char* __restrict__ idxb, const int* __restrict__ row,
        const int* __restrict__ col, const float* __restrict__ W2,
        float* __restrict__ acc, int E) {
    int wid = threadIdx.x >> 6;
    int lane = threadIdx.x & 63;
    int e = blockIdx.x * 4 + wid;
    __shared__ float sh[4][64];
    bool active = (e < E);
    int c = active ? col[e] : 0;
    if (active) sh[wid][lane] = h1[(size_t)c * 64 + lane];
    __syncthreads();
    if (!active) return;
    float m = 0.0f;
#pragma unroll
    for (int s = 0; s < 8; ++s) {
        const float* Wk = W2 + (size_t)idxb[(size_t)e * 8 + s] * 4096;
        float ms = 0.0f;
#pragma unroll
        for (int i = 0; i < 64; ++i) ms += sh[wid][i] * Wk[i * 64 + lane];
        m += basis[(size_t)e * 8 + s] * ms;
    }
    atomicAdd(&acc[(size_t)row[e] * 64 + lane], m);
}

__global__ __launch_bounds__(256) void conv3f_kernel(
        const float* __restrict__ x, const float* __restrict__ basis,
        const unsigned char* __restrict__ idxb, const int* __restrict__ row,
        const int* __restrict__ col, const float* __restrict__ Wc,
        float* __restrict__ acc, int E) {
    int wid = threadIdx.x >> 6;
    int lane = threadIdx.x & 63;
    int e = blockIdx.x * 4 + wid;
    __shared__ float sx[4][32];
    bool active = (e < E);
    int c = active ? col[e] : 0;
    if (active && lane < 32) sx[wid][lane] = x[(size_t)c * 32 + lane];
    __syncthreads();
    int half = lane >> 5;
    int o = lane & 31;
    float m = 0.0f;
    if (active) {
#pragma unroll
        for (int s2 = 0; s2 < 4; ++s2) {
            int s = half * 4 + s2;
            const float* Wk = Wc + (size_t)idxb[(size_t)e * 8 + s] * 1024;
            float ms = 0.0f;
#pragma unroll
            for (int i = 0; i < 32; ++i) ms += sx[wid][i] * Wk[i * 32 + o];
            m += basis[(size_t)e * 8 + s] * ms;
        }
    }
    m += __shfl_xor(m, 32);
    if (active && lane < 32) atomicAdd(&acc[(size_t)row[e] * 32 + o], m);
}

__global__ void finalize_kernel(const float* __restrict__ acc, const int* __restrict__ histR,
                                const float* __restrict__ bias, float* __restrict__ outF,
                                unsigned short* __restrict__ outB,
                                int N, int F, int do_elu) {
    int t = blockIdx.x * blockDim.x + threadIdx.x;
    if (t >= N * F) return;
    int n = t / F, o = t % F;
    float v = acc[t] / fmaxf((float)histR[n], 1.0f) + bias[o];
    if (do_elu) v = (v > 0.0f) ? v : (expf(v) - 1.0f);
    if (outF) outF[t] = v;
    if (outB) outB[t] = f2b(v);
}

extern "C" void kernel_launch(void* const* d_in, const int* in_sizes, int n_in,
                              void* d_out, int out_size, void* d_ws, size_t ws_size,
                              hipStream_t stream) {
    const float* x      = (const float*)d_in[0];
    const int*   ei     = (const int*)d_in[1];
    const float* pseudo = (const float*)d_in[2];
    const float* w1     = (const float*)d_in[3];
    const float* b1     = (const float*)d_in[4];
    const float* w2     = (const float*)d_in[5];
    const float* b2     = (const float*)d_in[6];
    const float* w3     = (const float*)d_in[7];
    const float* b3     = (const float*)d_in[8];
    const float* w4     = (const float*)d_in[9];
    const float* b4     = (const float*)d_in[10];
    const float* wc     = (const float*)d_in[11];
    const float* cb     = (const float*)d_in[12];
    float* out = (float*)d_out;

    const int N = in_sizes[0] / 32;
    const int E = in_sizes[1] / 2;
    const int* row = ei;
    const int* col = ei + E;
    const int KC = 125;

    char* p = (char*)d_ws;
    // zeroed: histograms
    int* histR = (int*)p; p += (size_t)N * sizeof(int);
    int* histC = (int*)p; p += (size_t)N * sizeof(int);
    size_t zero_bytes = (size_t)(p - (char*)d_ws);
    // non-zeroed
    int* cstart   = (int*)p; p += (size_t)N * sizeof(int);
    int* cursorC  = (int*)p; p += (size_t)N * sizeof(int);
    int* rowStart = (int*)p; p += (size_t)N * sizeof(int);
    int* cursorR  = (int*)p; p += (size_t)N * sizeof(int);
    int* jpos = (int*)p; p += (size_t)E * sizeof(int);
    int* colS = (int*)p; p += (size_t)E * sizeof(int);
    int* perm = (int*)p; p += (size_t)E * sizeof(int);
    float* h2 = (float*)p; p += (size_t)N * 64 * sizeof(float);
    float* tt = (float*)p; p += (size_t)N * 3 * sizeof(float);
    float* basis = (float*)p; p += (size_t)E * 8 * sizeof(float);
    unsigned char* idxb = (unsigned char*)p; p += (size_t)E * 8;
    unsigned short* h1b = (unsigned short*)p; p += (size_t)N * 64 * sizeof(short);
    unsigned short* xb  = (unsigned short*)p; p += (size_t)N * 32 * sizeof(short);
    unsigned short* BF2 = (unsigned short*)p; p += (size_t)KC * 64 * 64 * sizeof(short);
    unsigned short* BF3 = (unsigned short*)p; p += (size_t)KC * 32 * 32 * sizeof(short);
    unsigned short* msg = (unsigned short*)p; p += (size_t)E * 64 * sizeof(short);
    size_t fixed = (size_t)(p - (char*)d_ws);
    size_t zcap = (ws_size > fixed) ? (ws_size - fixed) : 0;
    unsigned short* zbuf = (unsigned short*)p;

    const size_t z_half = (size_t)N * KC * 32 * sizeof(short);   // 160MB
    const size_t z_quar = (size_t)N * KC * 16 * sizeof(short);   // 80MB
    int mode = (zcap >= z_half) ? 2 : (zcap >= z_quar ? 4 : 0);  // H2 split count

    hipMemsetAsync(d_ws, 0, zero_bytes, stream);
    hist_kernel<<<(E + 255) / 256, 256, 0, stream>>>(row, col, histR, histC, E);

    const int MT128 = (N + 127) / 128;

    if (mode) {
        const int H2 = mode;            // conv2 channel splits
        const int CH2 = 64 / H2;        // 32 or 16
        const int H3 = (mode == 2) ? 1 : 2;
        const int CH3 = 32 / H3;

        pack_w_kernel<<<(KC * 64 * 64 + 255) / 256, 256, 0, stream>>>(w2, BF2, KC, 64, 64, 2, CH2);
        pack_w_kernel<<<(KC * 32 * 32 + 255) / 256, 256, 0, stream>>>(wc, BF3, KC, 32, 32, 1, CH3);
        castbf_kernel<<<(N * 32 + 255) / 256, 256, 0, stream>>>(x, xb, N * 32);

        scan_kernel<<<1, 1024, 0, stream>>>(histC, cstart, cursorC, N);
        scan_kernel<<<1, 1024, 0, stream>>>(histR, rowStart, cursorR, N);
        scatter_kernel<<<(E + 255) / 256, 256, 0, stream>>>(row, col, cursorC, cursorR,
                                                            jpos, colS, perm, E);
        basis1_kernel<<<(E + 255) / 256, 256, 0, stream>>>(pseudo, jpos, basis, idxb, E);

        // conv1: fully fused phase B
        phaseB1_kernel<<<(N + 3) / 4, 256, 0, stream>>>(w1, basis, idxb, perm, rowStart,
                                                        histR, b1, h1b, N);
        // conv2: channel-split z
        for (int s = 0; s < H2; ++s) {
            int zct = KC * CH2 / 16;
            dim3 g(MT128, (zct + 3) / 4);
            zgemm_kernel<2><<<g, 256, 0, stream>>>(h1b, N, BF2, zbuf, KC * CH2, s * zct, zct);
            if (CH2 == 32)
                msgA_kernel<32, 4><<<(N + 3) / 4, 256, 0, stream>>>(
                    zbuf, basis, idxb, cstart, colS, msg, 64, s * 32, N, E);
            else
                msgA_kernel<16, 8><<<(N + 7) / 8, 256, 0, stream>>>(
                    zbuf, basis, idxb, cstart, colS, msg, 64, s * 16, N, E);
        }
        phaseB64_kernel<<<(N + 3) / 4, 256, 0, stream>>>(msg, perm, rowStart, histR, b2, h2, N);

        stn34_kernel<<<N, 64, 0, stream>>>(h2, w3, b3, w4, b4, tt, N);
        basis2_kernel<<<(E + 255) / 256, 256, 0, stream>>>(pseudo, tt, row, col, jpos,
                                                           basis, idxb, E);
        // conv3
        for (int s = 0; s < H3; ++s) {
            int zct = KC * CH3 / 16;
            dim3 g(MT128, (zct + 3) / 4);
            zgemm_kernel<1><<<g, 256, 0, stream>>>(xb, N, BF3, zbuf, KC * CH3, s * zct, zct);
            if (CH3 == 32)
                msgA_kernel<32, 4><<<(N + 3) / 4, 256, 0, stream>>>(
                    zbuf, basis, idxb, cstart, colS, msg, 32, 0, N, E);
            else
                msgA_kernel<16, 8><<<(N + 7) / 8, 256, 0, stream>>>(
                    zbuf, basis, idxb, cstart, colS, msg, 32, s * 16, N, E);
        }
        phaseB32_kernel<<<(N + 7) / 8, 256, 0, stream>>>(msg, perm, rowStart, histR, cb, out, N);
    } else {
        // tiny-ws fallback: direct convs with atomics (correct, slow)
        float* acc1 = (float*)msg;                 // alias into msg region
        float* acc2 = acc1 + (size_t)N * 64;
        float* acc3 = acc2 + (size_t)N * 64;
        float* h1f  = acc3 + (size_t)N * 32;
        size_t acc_bytes = (size_t)N * (64 + 64 + 32) * sizeof(float);
        hipMemsetAsync((void*)acc1, 0, acc_bytes, stream);

        basis1_kernel<<<(E + 255) / 256, 256, 0, stream>>>(pseudo, nullptr, basis, idxb, E);
        conv1_at_kernel<<<(E + 3) / 4, 256, 0, stream>>>(basis, idxb, row, w1, acc1, E);
        finalize_kernel<<<(N * 64 + 255) / 256, 256, 0, stream>>>(acc1, histR, b1, h1f, nullptr, N, 64, 1);
        conv2f_kernel<<<(E + 3) / 4, 256, 0, stream>>>(h1f, basis, idxb, row, col, w2, acc2, E);
        finalize_kernel<<<(N * 64 + 255) / 256, 256, 0, stream>>>(acc2, histR, b2, h2, nullptr, N, 64, 1);
        stn34_kernel<<<N, 64, 0, stream>>>(h2, w3, b3, w4, b4, tt, N);
        basis2_kernel<<<(E + 255) / 256, 256, 0, stream>>>(pseudo, tt, row, col, nullptr, basis, idxb, E);
        conv3f_kernel<<<(E + 3) / 4, 256, 0, stream>>>(x, basis, idxb, row, col, wc, acc3, E);
        finalize_kernel<<<(N * 32 + 255) / 256, 256, 0, stream>>>(acc3, histR, cb, out, nullptr, N, 32, 0);
    }
}